// Round 3
// baseline (542.465 us; speedup 1.0000x reference)
//
#include <hip/hip_runtime.h>
#include <hip/hip_bf16.h>
#include <stdint.h>

typedef _Float16 half8 __attribute__((ext_vector_type(8)));
typedef __attribute__((ext_vector_type(4))) float floatx4;
typedef __attribute__((ext_vector_type(4))) uint32_t uint32x4;

#define BM 128
#define BN 128
#define BK 64
#define NTHREADS 256
#define GROUP_SZ 128
#define TILE_B (BM * BK * 2)   // 16 KiB per operand tile

// XOR-swizzled byte offset inside a [row][128B] LDS tile (T2, 16B-slot granularity)
__device__ __forceinline__ uint32_t swz(uint32_t row, uint32_t byte_in_row) {
    return row * 128u + (byte_in_row ^ ((row & 7u) << 4));
}

__device__ __forceinline__ uint32_t cvt_pk_f16(float lo, float hi) {
    uint32_t r;
    asm("v_cvt_pkrtz_f16_f32 %0, %1, %2" : "=v"(r) : "v"(lo), "v"(hi));
    return r;
}
__device__ __forceinline__ uint32_t pk_add_f16(uint32_t a, uint32_t b) {
    uint32_t r;
    asm("v_pk_add_f16 %0, %1, %2" : "=v"(r) : "v"(a), "v"(b));
    return r;
}
__device__ __forceinline__ uint32_t pk_mul_f16(uint32_t a, uint32_t b) {
    uint32_t r;
    asm("v_pk_mul_f16 %0, %1, %2" : "=v"(r) : "v"(a), "v"(b));
    return r;
}

__global__ __launch_bounds__(NTHREADS, 2)
void gptq_gemm_kernel(const float* __restrict__ x,
                      const int* __restrict__ qweight,
                      const float* __restrict__ scales,
                      const int* __restrict__ qzeros,
                      float* __restrict__ out,
                      int M, int K, int N) {
    __shared__ char smem[2 * 2 * TILE_B];  // 64 KiB: 2 buffers x (A tile + B tile)

    const int nbm = M / BM, nbn = N / BN;
    const int nwg = nbm * nbn;
    // bijective XCD-aware swizzle (m204 formula)
    int bid = blockIdx.x;
    int q = nwg >> 3, r = nwg & 7;
    int xcd = bid & 7, lin = bid >> 3;
    int sid = (xcd < r ? xcd * (q + 1) : r * (q + 1) + (xcd - r) * q) + lin;
    int bm = sid / nbn, bn = sid % nbn;
    const int m0 = bm * BM, n0 = bn * BN;

    const int t = threadIdx.x;
    const int lane = t & 63, wave = t >> 6;

    // A staging: thread covers rows (i*16 + tm), k-quad tk4 (4 floats = 16B)
    const int tm = t >> 4;          // 0..15
    const int tk4 = t & 15;         // 0..15 -> k offset tk4*4
    // B staging: thread covers column sn, word-half kwh (4 words of 8 k each)
    const int sn = t & 127;         // 0..127
    const int kwh = t >> 7;         // 0..1

    const int gn = n0 + sn;
    const int NT = K / BK;

    // running global pointers (strength-reduced)
    const float* xp = x + (size_t)(m0 + tm) * K + tk4 * 4;
    const int*   qp = qweight + (size_t)(kwh * 4) * N + gn;
    const float* sp = scales + gn;
    const int*   zp = qzeros + (gn >> 3);
    const int    zsh = (gn & 7) * 4;

    // per-tile staging registers
    float4 av[8];
    uint32_t qw[4];
    float sc;
    uint32_t zw;

    auto load_tile = [&](int ts) {
        #pragma unroll
        for (int i = 0; i < 8; ++i)
            av[i] = *reinterpret_cast<const float4*>(xp + (size_t)i * 16 * K);
        xp += BK;
        #pragma unroll
        for (int j = 0; j < 4; ++j)
            qw[j] = (uint32_t)qp[(size_t)j * N];
        qp += (size_t)(BK / 8) * N;
        if ((ts & 1) == 0) {             // new quant group every 2 k-steps
            const int g = ts >> 1;
            sc = sp[(size_t)g * N];
            zw = (uint32_t)zp[(size_t)g * (N >> 3)];
        }
    };

    auto write_tile = [&](char* Ald, char* Bld) {
        // A: fp32 -> f16 packed
        #pragma unroll
        for (int i = 0; i < 8; ++i) {
            uint2 p;
            p.x = cvt_pk_f16(av[i].x, av[i].y);
            p.y = cvt_pk_f16(av[i].z, av[i].w);
            *reinterpret_cast<uint2*>(Ald + swz((uint32_t)(i * 16 + tm), (uint32_t)(tk4 * 8))) = p;
        }
        // group constants (packed f16): q_hat = 1024+q exact; c = -(1025+zq) exact int
        const float zf = -(float)(1025u + ((zw >> zsh) & 15u));
        const uint32_t c2 = cvt_pk_f16(zf, zf);
        const uint32_t s2 = cvt_pk_f16(sc, sc);
        // B: 4 words x 8 nibbles -> f16 via exponent-bias trick + packed math
        #pragma unroll
        for (int j = 0; j < 4; ++j) {
            const uint32_t w = qw[j];
            uint32_t o[4];
            #pragma unroll
            for (int i = 0; i < 4; ++i) {
                const uint32_t tt = w >> (8 * i);
                const uint32_t qi = ((tt & 0xFu) | 0x64006400u) | ((tt << 12) & 0xF0000u);
                o[i] = pk_mul_f16(pk_add_f16(qi, c2), s2);
            }
            uint4 p;
            p.x = o[0]; p.y = o[1]; p.z = o[2]; p.w = o[3];
            *reinterpret_cast<uint4*>(Bld + swz((uint32_t)sn, (uint32_t)((kwh * 4 + j) * 16))) = p;
        }
    };

    // accumulators: wave (wm,wn) owns 64x64 = 4x4 fragments of 16x16
    floatx4 acc[4][4];
    const floatx4 fzero = {0.f, 0.f, 0.f, 0.f};
    #pragma unroll
    for (int i = 0; i < 4; ++i)
        #pragma unroll
        for (int j = 0; j < 4; ++j)
            acc[i][j] = fzero;

    const int wm = (wave >> 1) * 64, wn = (wave & 1) * 64;
    const int fr = lane & 15;                 // fragment row (A) / col (B)
    const int fkb = ((lane >> 4) * 8) * 2;    // byte offset of this lane's 8-k chunk

    auto compute = [&](const char* Ald, const char* Bld) {
        #pragma unroll
        for (int kk = 0; kk < 2; ++kk) {
            half8 af[4], bf[4];
            #pragma unroll
            for (int i = 0; i < 4; ++i) {
                uint32x4 u = *reinterpret_cast<const uint32x4*>(
                    Ald + swz((uint32_t)(wm + i * 16 + fr), (uint32_t)(kk * 64 + fkb)));
                af[i] = __builtin_bit_cast(half8, u);
            }
            #pragma unroll
            for (int i = 0; i < 4; ++i) {
                uint32x4 u = *reinterpret_cast<const uint32x4*>(
                    Bld + swz((uint32_t)(wn + i * 16 + fr), (uint32_t)(kk * 64 + fkb)));
                bf[i] = __builtin_bit_cast(half8, u);
            }
            #pragma unroll
            for (int i = 0; i < 4; ++i)
                #pragma unroll
                for (int j = 0; j < 4; ++j)
                    acc[i][j] = __builtin_amdgcn_mfma_f32_16x16x32_f16(af[i], bf[j], acc[i][j], 0, 0, 0);
        }
    };

    // ---- main loop: double-buffered LDS, ONE barrier per k-step ----
    load_tile(0);
    write_tile(smem, smem + TILE_B);
    int cur = 0;
    for (int ts = 0; ts < NT; ++ts) {
        __syncthreads();                       // buf[cur] fully written
        if (ts + 1 < NT) load_tile(ts + 1);    // issue loads early (hide under MFMA)
        char* base = smem + cur * (2 * TILE_B);
        compute(base, base + TILE_B);
        if (ts + 1 < NT) {
            char* nbase = smem + (cur ^ 1) * (2 * TILE_B);
            write_tile(nbase, nbase + TILE_B); // writes other buffer; no barrier needed
        }
        cur ^= 1;
    }

    // ---- epilogue: C/D layout col=lane&15, row=(lane>>4)*4+reg ----
    const int fq = lane >> 4;
    float* op = out + (size_t)(m0 + wm) * N + n0 + wn;
    #pragma unroll
    for (int i = 0; i < 4; ++i)
        #pragma unroll
        for (int j = 0; j < 4; ++j)
            #pragma unroll
            for (int rr = 0; rr < 4; ++rr)
                op[(size_t)(i * 16 + fq * 4 + rr) * N + j * 16 + fr] = acc[i][j][rr];
}

extern "C" void kernel_launch(void* const* d_in, const int* in_sizes, int n_in,
                              void* d_out, int out_size, void* d_ws, size_t ws_size,
                              hipStream_t stream) {
    const float* x       = (const float*)d_in[0];
    const int*   qweight = (const int*)d_in[1];
    const float* scales  = (const float*)d_in[2];
    const int*   qzeros  = (const int*)d_in[3];

    const int K = in_sizes[4];
    const int M = in_sizes[0] / K;
    const int G = K / GROUP_SZ;
    const int N = in_sizes[2] / G;
    float* out = (float*)d_out;

    const int nwg = (M / BM) * (N / BN);
    hipLaunchKernelGGL(gptq_gemm_kernel, dim3(nwg), dim3(NTHREADS), 0, stream,
                       x, qweight, scales, qzeros, out, M, K, N);
}

// Round 4
// 412.775 us; speedup vs baseline: 1.3142x; 1.3142x over previous
//
#include <hip/hip_runtime.h>
#include <hip/hip_bf16.h>
#include <stdint.h>

typedef _Float16 half8 __attribute__((ext_vector_type(8)));
typedef __attribute__((ext_vector_type(8))) short short8;
typedef __attribute__((ext_vector_type(4))) float floatx4;
typedef __attribute__((ext_vector_type(4))) uint32_t uint32x4;

#define GROUP_SZ 128

__device__ __forceinline__ uint32_t cvt_pk_f16(float lo, float hi) {
    uint32_t r;
    asm("v_cvt_pkrtz_f16_f32 %0, %1, %2" : "=v"(r) : "v"(lo), "v"(hi));
    return r;
}
__device__ __forceinline__ uint32_t pk_add_f16(uint32_t a, uint32_t b) {
    uint32_t r;
    asm("v_pk_add_f16 %0, %1, %2" : "=v"(r) : "v"(a), "v"(b));
    return r;
}
__device__ __forceinline__ uint32_t pk_mul_f16(uint32_t a, uint32_t b) {
    uint32_t r;
    asm("v_pk_mul_f16 %0, %1, %2" : "=v"(r) : "v"(a), "v"(b));
    return r;
}

// ============================== prepass: A fp32 -> f16 plain [M][K] ==========
__global__ __launch_bounds__(256)
void convA_kernel(const float* __restrict__ x, uint4* __restrict__ aws, int total8) {
    int idx = blockIdx.x * 256 + threadIdx.x;
    if (idx >= total8) return;
    const float4* xp = reinterpret_cast<const float4*>(x) + (size_t)idx * 2;
    float4 a = xp[0], b = xp[1];
    uint4 o;
    o.x = cvt_pk_f16(a.x, a.y);
    o.y = cvt_pk_f16(a.z, a.w);
    o.z = cvt_pk_f16(b.x, b.y);
    o.w = cvt_pk_f16(b.z, b.w);
    aws[idx] = o;
}

// ==== prepass: dequant B -> f16 tiled slot-major [nt][kt][h][slot][row][16B] =
__global__ __launch_bounds__(256)
void deqB_kernel(const int* __restrict__ qw, const float* __restrict__ sc,
                 const int* __restrict__ qz, char* __restrict__ bws, int K, int N) {
    const int n = blockIdx.x * 256 + threadIdx.x;
    const int wk = blockIdx.y;               // word-row: 8 k's
    if (n >= N) return;
    const uint32_t w = (uint32_t)qw[(size_t)wk * N + n];
    const int g = wk >> 4;                   // k/128
    const float s = sc[(size_t)g * N + n];
    const uint32_t zw = (uint32_t)qz[(size_t)g * (N >> 3) + (n >> 3)];
    const float zf = -(float)(1025u + ((zw >> ((n & 7) * 4)) & 15u));
    const uint32_t c2 = cvt_pk_f16(zf, zf);
    const uint32_t s2 = cvt_pk_f16(s, s);
    uint32_t oo[4];
    #pragma unroll
    for (int i = 0; i < 4; ++i) {
        const uint32_t tt = w >> (8 * i);
        const uint32_t qi = ((tt & 0xFu) | 0x64006400u) | ((tt << 12) & 0xF0000u);
        oo[i] = pk_mul_f16(pk_add_f16(qi, c2), s2);
    }
    uint4 o; o.x = oo[0]; o.y = oo[1]; o.z = oo[2]; o.w = oo[3];
    const int NKT = K >> 6;
    const int nt = n >> 8, h = (n >> 7) & 1, row = n & 127;
    const int kt = wk >> 3, slot = wk & 7;
    size_t off = ((((size_t)nt * NKT + kt) * 2 + h) * 8 + slot) * 2048 + (size_t)row * 16;
    *reinterpret_cast<uint4*>(bws + off) = o;
}

// ===================== main: 256x256 8-phase f16 GEMM ========================
__global__ __launch_bounds__(512, 2)
void gemm8_kernel(const char* __restrict__ Aws, const char* __restrict__ Bws,
                  float* __restrict__ out, int M, int K, int N) {
    __shared__ char smem[131072];  // 2 bufs x (A 32KB + B 32KB)

    const int NT = K >> 6;
    const int nbm = M >> 8, nbn = N >> 8;
    const int nwg = nbm * nbn;
    int bid = blockIdx.x;
    int q = nwg >> 3, r = nwg & 7;
    int xcd = bid & 7, lin = bid >> 3;
    int sid = (xcd < r ? xcd * (q + 1) : r * (q + 1) + (xcd - r) * q) + lin;
    const int bm = sid / nbn, bn = sid % nbn;
    const int m0 = bm << 8, n0 = bn << 8;

    const int tid = threadIdx.x;
    const int lane = tid & 63, w = tid >> 6;
    const int wm = w >> 2, wn = w & 3;       // 2 x 4 waves
    const int fr = lane & 15, hi = lane >> 4;
    const int r8 = lane >> 3, c8 = lane & 7;

    // ---- staging source pointers ----
    const size_t K2 = (size_t)K * 2;
    const char* aSrc[2][2];
    #pragma unroll
    for (int h = 0; h < 2; ++h)
        #pragma unroll
        for (int i = 0; i < 2; ++i)
            aSrc[h][i] = Aws + (size_t)(m0 + h * 128 + w * 16 + i * 8 + r8) * K2
                             + (size_t)((c8 ^ r8) * 16);
    const char* bSrc = Bws + (size_t)bn * ((size_t)NT * 32768)
                           + (size_t)w * 2048 + (size_t)lane * 16;

    auto stageA = [&](uint32_t buf, int h, int kt) {
        #pragma unroll
        for (int i = 0; i < 2; ++i) {
            const char* src = aSrc[h][i] + (size_t)kt * 128;
            char* dst = smem + buf * 65536u + (uint32_t)h * 16384u
                             + (uint32_t)w * 2048u + (uint32_t)i * 1024u;
            __builtin_amdgcn_global_load_lds(
                (const __attribute__((address_space(1))) void*)src,
                (__attribute__((address_space(3))) void*)dst, 16, 0, 0);
        }
    };
    auto stageB = [&](uint32_t buf, int h, int kt) {
        #pragma unroll
        for (int i = 0; i < 2; ++i) {
            const char* src = bSrc + ((size_t)kt * 2 + h) * 16384 + (size_t)i * 1024;
            char* dst = smem + buf * 65536u + 32768u + (uint32_t)h * 16384u
                             + (uint32_t)w * 2048u + (uint32_t)i * 1024u;
            __builtin_amdgcn_global_load_lds(
                (const __attribute__((address_space(1))) void*)src,
                (__attribute__((address_space(3))) void*)dst, 16, 0, 0);
        }
    };

    // ---- accumulators / fragments ----
    floatx4 acc[8][4];
    const floatx4 fz = {0.f, 0.f, 0.f, 0.f};
    #pragma unroll
    for (int i = 0; i < 8; ++i)
        #pragma unroll
        for (int j = 0; j < 4; ++j) acc[i][j] = fz;
    half8 af[4][2];      // current qm-half A fragments
    half8 bf[2][2][2];   // all B fragments for the K-tile

#define LOAD_AF(QM) { _Pragma("unroll") for (int fmi = 0; fmi < 4; ++fmi) { \
    _Pragma("unroll") for (int kk = 0; kk < 2; ++kk) { \
        uint32_t row = (uint32_t)(wm * 128 + ((QM) * 4 + fmi) * 16 + fr); \
        uint32_t p = (uint32_t)((kk * 4 + hi) ^ (fr & 7)); \
        uint32x4 u = *reinterpret_cast<const uint32x4*>(As + row * 128u + p * 16u); \
        af[fmi][kk] = __builtin_bit_cast(half8, u); } } }

#define LOAD_BF(QN) { _Pragma("unroll") for (int fnj = 0; fnj < 2; ++fnj) { \
    _Pragma("unroll") for (int kk = 0; kk < 2; ++kk) { \
        uint32_t nl = (uint32_t)(wn * 64 + ((QN) * 2 + fnj) * 16 + fr); \
        uint32_t off = (nl >> 7) * 16384u + (uint32_t)(kk * 4 + hi) * 2048u + (nl & 127u) * 16u; \
        uint32x4 u = *reinterpret_cast<const uint32x4*>(Bs + off); \
        bf[QN][fnj][kk] = __builtin_bit_cast(half8, u); } } }

#define MM(QM, QN) { _Pragma("unroll") for (int fmi = 0; fmi < 4; ++fmi) \
    _Pragma("unroll") for (int fnj = 0; fnj < 2; ++fnj) \
    _Pragma("unroll") for (int kk = 0; kk < 2; ++kk) \
        acc[(QM) * 4 + fmi][(QN) * 2 + fnj] = __builtin_amdgcn_mfma_f32_16x16x32_f16( \
            af[fmi][kk], bf[QN][fnj][kk], acc[(QM) * 4 + fmi][(QN) * 2 + fnj], 0, 0, 0); }

#define WAIT_LGKM() asm volatile("s_waitcnt lgkmcnt(0)" ::: "memory"); \
                    __builtin_amdgcn_sched_barrier(0)

    // ---- prologue: tile0 fully + tile1 A-halves ----
    stageA(0, 0, 0); stageA(0, 1, 0); stageB(0, 0, 0); stageB(0, 1, 0);
    if (NT > 1) { stageA(1, 0, 1); stageA(1, 1, 1); }
    asm volatile("s_waitcnt vmcnt(4)" ::: "memory");
    __builtin_amdgcn_s_barrier();

    for (int t = 0; t < NT; ++t) {
        const uint32_t c = (uint32_t)(t & 1), nb = c ^ 1u;
        const char* As = smem + c * 65536u;
        const char* Bs = As + 32768u;
        const bool st1 = (t + 1 < NT);
        // ---- phase 0: af(qm0) + bf(qn0); stage B h0 of t+1 ----
        LOAD_AF(0); LOAD_BF(0);
        if (st1) stageB(nb, 0, t + 1);
        __builtin_amdgcn_s_barrier();
        WAIT_LGKM();
        __builtin_amdgcn_s_setprio(1); MM(0, 0); __builtin_amdgcn_s_setprio(0);
        __builtin_amdgcn_sched_barrier(0);
        __builtin_amdgcn_s_barrier();
        // ---- phase 1: bf(qn1); stage B h1 of t+1 ----
        LOAD_BF(1);
        if (st1) stageB(nb, 1, t + 1);
        __builtin_amdgcn_s_barrier();
        WAIT_LGKM();
        __builtin_amdgcn_s_setprio(1); MM(0, 1); __builtin_amdgcn_s_setprio(0);
        __builtin_amdgcn_sched_barrier(0);
        __builtin_amdgcn_s_barrier();
        // ---- phase 2: af(qm1) ----
        LOAD_AF(1);
        __builtin_amdgcn_s_barrier();
        WAIT_LGKM();
        __builtin_amdgcn_s_setprio(1); MM(1, 0); __builtin_amdgcn_s_setprio(0);
        __builtin_amdgcn_sched_barrier(0);
        __builtin_amdgcn_s_barrier();
        // ---- phase 3 ----
        __builtin_amdgcn_s_barrier();
        __builtin_amdgcn_s_setprio(1); MM(1, 1); __builtin_amdgcn_s_setprio(0);
        __builtin_amdgcn_sched_barrier(0);
        __builtin_amdgcn_s_barrier();
        // ---- boundary: stage A halves of t+2 into buf c; counted vmcnt ----
        if (st1) {
            if (t + 2 < NT) {
                stageA(c, 0, t + 2); stageA(c, 1, t + 2);
                asm volatile("s_waitcnt vmcnt(4)" ::: "memory");
            } else {
                asm volatile("s_waitcnt vmcnt(0)" ::: "memory");
            }
            __builtin_amdgcn_s_barrier();
        }
    }
#undef LOAD_AF
#undef LOAD_BF
#undef MM
#undef WAIT_LGKM

    // ---- epilogue: C/D layout col=lane&15, row=(lane>>4)*4+reg ----
    float* op = out + (size_t)(m0 + wm * 128) * N + n0 + wn * 64;
    #pragma unroll
    for (int fm = 0; fm < 8; ++fm)
        #pragma unroll
        for (int fn = 0; fn < 4; ++fn)
            #pragma unroll
            for (int rr = 0; rr < 4; ++rr)
                op[(size_t)(fm * 16 + hi * 4 + rr) * N + fn * 16 + fr] = acc[fm][fn][rr];
}

// ================= fallback: fused 128x128 kernel (verified R1) ==============
__device__ __forceinline__ uint32_t cvt_pk_bf16(float lo, float hi) {
    uint32_t r;
    asm("v_cvt_pk_bf16_f32 %0, %1, %2" : "=v"(r) : "v"(lo), "v"(hi));
    return r;
}
__device__ __forceinline__ uint32_t fswz(uint32_t row, uint32_t byte_in_row) {
    return row * 128u + (byte_in_row ^ ((row & 7u) << 4));
}

__global__ __launch_bounds__(256, 2)
void fused128_kernel(const float* __restrict__ x, const int* __restrict__ qweight,
                     const float* __restrict__ scales, const int* __restrict__ qzeros,
                     float* __restrict__ out, int M, int K, int N) {
    __shared__ char smem[32768];
    char* Ald = smem;
    char* Bld = smem + 16384;
    const int nbm = M / 128, nbn = N / 128;
    const int nwg = nbm * nbn;
    int bid = blockIdx.x;
    int q = nwg >> 3, r = nwg & 7;
    int xcd = bid & 7, lin = bid >> 3;
    int sid = (xcd < r ? xcd * (q + 1) : r * (q + 1) + (xcd - r) * q) + lin;
    int bm = sid / nbn, bn = sid % nbn;
    const int m0 = bm * 128, n0 = bn * 128;
    const int t = threadIdx.x;
    const int lane = t & 63, wave = t >> 6;
    const int tm = t >> 4, tk4 = t & 15;
    const int sn = t & 127, kwh = t >> 7;
    const int gn = n0 + sn;
    const int NT = K / 64;
    float4 av[8]; uint32_t qw[4]; float sc; uint32_t zw;
    const float* xp = x + (size_t)(m0 + tm) * K + tk4 * 4;
    const int* qp = qweight + (size_t)(kwh * 4) * N + gn;
    auto load_tile = [&](int ts) {
        const int k0 = ts * 64;
        #pragma unroll
        for (int i = 0; i < 8; ++i)
            av[i] = *reinterpret_cast<const float4*>(xp + (size_t)i * 16 * K + k0);
        const int g = k0 >> 7;
        sc = scales[(size_t)g * N + gn];
        zw = (uint32_t)qzeros[(size_t)g * (N >> 3) + (gn >> 3)];
        const int* qb = qp + (size_t)(k0 >> 3) * N;
        #pragma unroll
        for (int j = 0; j < 4; ++j) qw[j] = (uint32_t)qb[(size_t)j * N];
    };
    const int zsh = (gn & 7) * 4;
    auto write_tile = [&]() {
        #pragma unroll
        for (int i = 0; i < 8; ++i) {
            uint2 p;
            p.x = cvt_pk_bf16(av[i].x, av[i].y);
            p.y = cvt_pk_bf16(av[i].z, av[i].w);
            *reinterpret_cast<uint2*>(Ald + fswz((uint32_t)(i * 16 + tm), (uint32_t)(tk4 * 8))) = p;
        }
        const float z = (float)((zw >> zsh) & 15u) + 1.0f;
        const float nz = -z * sc;
        #pragma unroll
        for (int j = 0; j < 4; ++j) {
            const uint32_t wv = qw[j];
            float f[8];
            #pragma unroll
            for (int e = 0; e < 8; ++e)
                f[e] = fmaf((float)((wv >> (4 * e)) & 15u), sc, nz);
            uint4 p;
            p.x = cvt_pk_bf16(f[0], f[1]); p.y = cvt_pk_bf16(f[2], f[3]);
            p.z = cvt_pk_bf16(f[4], f[5]); p.w = cvt_pk_bf16(f[6], f[7]);
            *reinterpret_cast<uint4*>(Bld + fswz((uint32_t)sn, (uint32_t)((kwh * 4 + j) * 16))) = p;
        }
    };
    floatx4 acc[4][4];
    const floatx4 fz = {0.f, 0.f, 0.f, 0.f};
    #pragma unroll
    for (int i = 0; i < 4; ++i)
        #pragma unroll
        for (int j = 0; j < 4; ++j) acc[i][j] = fz;
    const int wm = (wave >> 1) * 64, wn = (wave & 1) * 64;
    const int fr = lane & 15;
    const int fkb = ((lane >> 4) * 8) * 2;
    auto compute = [&]() {
        #pragma unroll
        for (int kk = 0; kk < 2; ++kk) {
            short8 afv[4], bfv[4];
            #pragma unroll
            for (int i = 0; i < 4; ++i)
                afv[i] = *reinterpret_cast<const short8*>(
                    Ald + fswz((uint32_t)(wm + i * 16 + fr), (uint32_t)(kk * 64 + fkb)));
            #pragma unroll
            for (int i = 0; i < 4; ++i)
                bfv[i] = *reinterpret_cast<const short8*>(
                    Bld + fswz((uint32_t)(wn + i * 16 + fr), (uint32_t)(kk * 64 + fkb)));
            #pragma unroll
            for (int i = 0; i < 4; ++i)
                #pragma unroll
                for (int j = 0; j < 4; ++j)
                    acc[i][j] = __builtin_amdgcn_mfma_f32_16x16x32_bf16(afv[i], bfv[j], acc[i][j], 0, 0, 0);
        }
    };
    load_tile(0);
    write_tile();
    __syncthreads();
    for (int ts = 0; ts < NT; ++ts) {
        if (ts + 1 < NT) load_tile(ts + 1);
        compute();
        __syncthreads();
        if (ts + 1 < NT) write_tile();
        __syncthreads();
    }
    const int fq = lane >> 4;
    float* op = out + (size_t)(m0 + wm) * N + n0 + wn;
    #pragma unroll
    for (int i = 0; i < 4; ++i)
        #pragma unroll
        for (int j = 0; j < 4; ++j)
            #pragma unroll
            for (int rr = 0; rr < 4; ++rr)
                op[(size_t)(i * 16 + fq * 4 + rr) * N + j * 16 + fr] = acc[i][j][rr];
}

// ============================================================================
extern "C" void kernel_launch(void* const* d_in, const int* in_sizes, int n_in,
                              void* d_out, int out_size, void* d_ws, size_t ws_size,
                              hipStream_t stream) {
    const float* x       = (const float*)d_in[0];
    const int*   qweight = (const int*)d_in[1];
    const float* scales  = (const float*)d_in[2];
    const int*   qzeros  = (const int*)d_in[3];

    const int K = in_sizes[4];
    const int M = in_sizes[0] / K;
    const int G = K / GROUP_SZ;
    const int N = in_sizes[2] / G;
    float* out = (float*)d_out;

    const size_t needA = (size_t)M * K * 2;
    const size_t needB = (size_t)K * (size_t)N * 2;
    const bool ok = (ws_size >= needA + needB) && (M % 256 == 0) && (N % 256 == 0)
                    && (K % 128 == 0) && (N % 8 == 0);
    if (ok) {
        char* aws = (char*)d_ws;
        char* bws = aws + needA;
        const int total8 = M * (K / 8);
        hipLaunchKernelGGL(convA_kernel, dim3((total8 + 255) / 256), dim3(256), 0, stream,
                           x, (uint4*)aws, total8);
        hipLaunchKernelGGL(deqB_kernel, dim3((N + 255) / 256, K / 8), dim3(256), 0, stream,
                           qweight, scales, qzeros, bws, K, N);
        hipLaunchKernelGGL(gemm8_kernel, dim3((M / 256) * (N / 256)), dim3(512), 0, stream,
                           aws, bws, out, M, K, N);
    } else {
        const int nwg = (M / 128) * (N / 128);
        hipLaunchKernelGGL(fused128_kernel, dim3(nwg), dim3(256), 0, stream,
                           x, qweight, scales, qzeros, out, M, K, N);
    }
}